// Round 6
// baseline (188.019 us; speedup 1.0000x reference)
//
#include <hip/hip_runtime.h>

#define Nn 100000
#define Tt 16
#define Dd 8
#define Hh 40
#define HP1 41

// ---- gram geometry (fixed) ----
#define SPC 8                  // 32-k steps per chunk
#define CH  (32 * SPC)         // 256 n per chunk
#define KCMAX ((Nn + CH - 1) / CH)    // 391 chunks

// ---- pair-symmetric slab: i<=j<50 pairs x 16 t ----
#define NPAIR 1275
#define PSZ (NPAIR * 16)       // 20400 floats per slab

// ---- workspace layout (float slots) ----
#define XEH_OFF  0                     // XeHi [64][Nn] f16 -> 32*Nn float slots
#define XEL_OFF  (XEH_OFF + 32 * Nn)   // XeLo [64][Nn] f16
#define PHIT_OFF (XEL_OFF + 32 * Nn)   // PhiT [16][Nn] f32
#define PART_OFF (PHIT_OFF + 16 * Nn)  // 8 * PSZ partials
#define P_OFF    (PART_OFF + 8 * PSZ)  // slabs

// output offsets (flat, return order)
#define OFF_BG1   0
#define OFF_BG2   16
#define OFF_MU    32
#define OFF_KAPPA 160
#define OFF_NU    176
#define OFF_PSI   192
#define OFF_WM    1216
#define OFF_WS    1872
#define OFF_ZA    28768
#define OFF_ZB    28784
#define OFF_EA    28800
#define OFF_EB    28816

typedef _Float16 f16x8 __attribute__((ext_vector_type(8)));
typedef float f32x4 __attribute__((ext_vector_type(4)));
typedef unsigned int u32x4 __attribute__((ext_vector_type(4)));

__device__ __forceinline__ int pidx(int i, int j) {
  if (i > j) { int tmp = i; i = j; j = tmp; }
  return (i * (2 * 50 - i + 1)) / 2 + (j - i);
}

// ---------------- Kernel 0: ELM expansion -> XeHi/XeLo planes + PhiT ------
// Xe row layout c: [h0..h39, 1, x0..x7, y, 0...0] (c=50..63 zero)
__global__ __launch_bounds__(256)
void elm_expand(const float* __restrict__ Phi, const float* __restrict__ Xd,
                const float* __restrict__ Yd, const float* __restrict__ W,
                const float* __restrict__ bb,
                unsigned short* __restrict__ XeHi, unsigned short* __restrict__ XeLo,
                float* __restrict__ PhiT)
{
  __shared__ float sW[Dd * Hh];
  __shared__ float sb[Hh];
  __shared__ float xs[64][9];
  __shared__ float ys[64];
  __shared__ float hrow[64][41];
  __shared__ float pt[16][68];
  int tid = threadIdx.x;
  int n0 = blockIdx.x * 64;

  for (int i = tid; i < Dd * Hh; i += 256) sW[i] = W[i];
  if (tid < Hh) sb[tid] = bb[tid];
  if (tid < 128) {
    int nl = tid >> 1, h4 = (tid & 1) * 4;
    int gn = n0 + nl;
    float4 v = (gn < Nn) ? *(const float4*)(Xd + (size_t)gn * 8 + h4)
                         : make_float4(0.f, 0.f, 0.f, 0.f);
    xs[nl][h4 + 0] = v.x; xs[nl][h4 + 1] = v.y;
    xs[nl][h4 + 2] = v.z; xs[nl][h4 + 3] = v.w;
  }
  if (tid < 64) { int gn = n0 + tid; ys[tid] = (gn < Nn) ? Yd[gn] : 0.f; }
  {
    int nl = tid >> 2, q = tid & 3;
    int gn = n0 + nl;
    float4 v = (gn < Nn) ? *(const float4*)(Phi + (size_t)gn * 16 + q * 4)
                         : make_float4(0.f, 0.f, 0.f, 0.f);
    pt[q * 4 + 0][nl] = v.x; pt[q * 4 + 1][nl] = v.y;
    pt[q * 4 + 2][nl] = v.z; pt[q * 4 + 3][nl] = v.w;
  }
  __syncthreads();
  // sigmoids: thread -> (n, 10 h's)
  {
    int nl = tid >> 2, hq = (tid & 3) * 10;
    for (int hh = 0; hh < 10; ++hh) {
      int h = hq + hh;
      float z = sb[h];
#pragma unroll
      for (int d = 0; d < 8; ++d) z = fmaf(xs[nl][d], sW[d * Hh + h], z);
      hrow[nl][h] = 1.f / (1.f + __expf(-z));
    }
  }
  __syncthreads();
  // PhiT write: thread (t = tid&15, nq = tid>>4) -> float4
  {
    int t = tid & 15, nq = tid >> 4;
    int gn = n0 + nq * 4;
    if (gn < Nn) {
      float4 v = make_float4(pt[t][nq * 4 + 0], pt[t][nq * 4 + 1],
                             pt[t][nq * 4 + 2], pt[t][nq * 4 + 3]);
      *(float4*)(PhiT + (size_t)t * Nn + gn) = v;
    }
  }
  // Xe hi/lo planes: thread (c = tid>>2, seg = tid&3) covers 16 n's
  {
    int cidx = tid >> 2, seg = tid & 3;
    int nl0 = seg * 16;
    float vv[16];
#pragma unroll
    for (int j = 0; j < 16; ++j) {
      int n = nl0 + j;
      float v;
      if (cidx < Hh) v = hrow[n][cidx];
      else if (cidx == 40) v = 1.f;
      else if (cidx < 49) v = xs[n][cidx - 41];
      else if (cidx == 49) v = ys[n];
      else v = 0.f;
      vv[j] = v;
    }
    unsigned short hs[16], ls[16];
#pragma unroll
    for (int j = 0; j < 16; ++j) {
      _Float16 h = (_Float16)vv[j];
      float r = vv[j] - (float)h;
      _Float16 lo = (_Float16)r;
      hs[j] = __builtin_bit_cast(unsigned short, h);
      ls[j] = __builtin_bit_cast(unsigned short, lo);
    }
#pragma unroll
    for (int q2 = 0; q2 < 2; ++q2) {
      int gn = n0 + nl0 + q2 * 8;
      if (gn < Nn) {
        uint4 uh, ul;
        uh.x = hs[q2*8+0] | ((unsigned)hs[q2*8+1] << 16);
        uh.y = hs[q2*8+2] | ((unsigned)hs[q2*8+3] << 16);
        uh.z = hs[q2*8+4] | ((unsigned)hs[q2*8+5] << 16);
        uh.w = hs[q2*8+6] | ((unsigned)hs[q2*8+7] << 16);
        ul.x = ls[q2*8+0] | ((unsigned)ls[q2*8+1] << 16);
        ul.y = ls[q2*8+2] | ((unsigned)ls[q2*8+3] << 16);
        ul.z = ls[q2*8+4] | ((unsigned)ls[q2*8+5] << 16);
        ul.w = ls[q2*8+6] | ((unsigned)ls[q2*8+7] << 16);
        *(uint4*)(XeHi + (size_t)cidx * Nn + gn) = uh;
        *(uint4*)(XeLo + (size_t)cidx * Nn + gn) = ul;
      }
    }
  }
}

// ---------------- Kernel 1: MFMA Gram, 391 chunks, 2 blocks/CU co-resident --------
// One block per K-chunk (grid-stride if ws-limited). 8 waves cover 52 i-rows.
// A rows are a SUBSET of B rows: staged B hi/lo planes serve both operands.
// LDS (48KB): 4 ring buffers x 8KB (Bhi[64][32k]f16 @0, Blo @4096), then static
// phi region [8 steps][16 t][32 k]f32 (16KB, staged once per chunk).
// Swizzles (source-preswizzled, linear LDS dest; same involution on ds_read):
//   B granule' = g ^ (row&3); phi granule' = g ^ (t&7).
// Pipeline: prologue stages phi + steps 0..2; loop s: s_waitcnt vmcnt(2|1|0),
// s_barrier (stages s+1,s+2 stay in flight), STAGE(s+3), compute.
// Slab output: pair-symmetric (i<=j<50), 20400 floats.
__device__ __forceinline__ void gload16(const void* g, void* l) {
  __builtin_amdgcn_global_load_lds(
      (const __attribute__((address_space(1))) unsigned int*)g,
      (__attribute__((address_space(3))) unsigned int*)l, 16, 0, 0);
}

#define PHI_LDS 32768                       // byte offset of phi region
#define LDS_BYTES (PHI_LDS + 16 * CH * 4)   // 32768 + 16384 = 49152

__global__ __launch_bounds__(512, 2)
void gram_mfma(const float* __restrict__ PhiT,
               const unsigned short* __restrict__ XeHi,
               const unsigned short* __restrict__ XeLo,
               float* __restrict__ P)
{
  __shared__ __align__(16) char smem[LDS_BYTES];

  int tid = threadIdx.x;
  int l = tid & 63, w = tid >> 6;
  int l15 = l & 15, lg = l >> 4;

  // per-wave M-tile range: waves 0-3 own 7 tiles, 4-7 own 6 (total 52)
  int MT  = (w < 4) ? 7 : 6;
  int i0w = (w < 4) ? 7 * w : 28 + 6 * (w - 4);

  // ---- static read offsets (bytes) ----
  int off_b[4];
#pragma unroll
  for (int nt = 0; nt < 4; ++nt) {
    int j = l15 + 16 * nt;
    off_b[nt] = j * 64 + 16 * (lg ^ (j & 3));
  }
  int off_a[7];
#pragma unroll
  for (int mi = 0; mi < 7; ++mi) {
    int i = i0w + mi;              // <= 52; rows >= 50 are exact zeros
    off_a[mi] = i * 64 + 16 * (lg ^ (i & 3));
  }
  int off_p0 = l15 * 128 + 16 * ((2 * lg) ^ (l15 & 7));
  int off_p1 = l15 * 128 + 16 * ((2 * lg + 1) ^ (l15 & 7));
  int ld0 = tid * 16;              // linear LDS stage dest (within buffer)
  int brow = (tid & 255) >> 2, bsl = tid & 3;   // B stage decode
  const unsigned short* bplane = (tid < 256) ? XeHi : XeLo;  // wave-uniform

  f32x4 acc[7][4];
#pragma unroll
  for (int mi = 0; mi < 7; ++mi)
#pragma unroll
    for (int nt = 0; nt < 4; ++nt) acc[mi][nt] = (f32x4){0.f, 0.f, 0.f, 0.f};

  for (int cc = blockIdx.x; cc < KCMAX; cc += gridDim.x) {
    int n0 = cc * CH;
    int rem = Nn - n0; if (rem > CH) rem = CH;
    int nsteps = rem >> 5;         // 8 (or 5 for the last chunk)

    // protect LDS reuse across segments (harmless on first)
    __builtin_amdgcn_s_barrier();
    asm volatile("" ::: "memory");

    // B stage source base for step 0 (advance 64B/step)
    const char* gB = (const char*)(bplane + (size_t)brow * Nn + n0
                                   + 8 * (bsl ^ (brow & 3)));
#define STAGE(sx) gload16(gB + (size_t)(sx) * 64, \
                          &smem[(((sx) & 3) * 8192) + ld0])

    // phi prologue: stage [SPC][16][32] f32 (1024 granules), pre-swizzled
#pragma unroll
    for (int q = 0; q < 2; ++q) {
      int gp = tid + q * 512;
      int s = gp >> 7, qq = gp & 127, t = qq >> 3, sl = qq & 7;
      gload16(PhiT + (size_t)t * Nn + n0 + s * 32 + 4 * (sl ^ (t & 7)),
              &smem[PHI_LDS + gp * 16]);
    }
    STAGE(0);
    if (nsteps > 1) STAGE(1);
    if (nsteps > 2) STAGE(2);

    for (int s = 0; s < nsteps; ++s) {
      // counted wait: stage s landed; stages s+1,s+2 stay in flight
      int out = nsteps - 1 - s; if (out > 2) out = 2;
      if (out == 2)      asm volatile("s_waitcnt vmcnt(2)" ::: "memory");
      else if (out == 1) asm volatile("s_waitcnt vmcnt(1)" ::: "memory");
      else               asm volatile("s_waitcnt vmcnt(0)" ::: "memory");
      __builtin_amdgcn_s_barrier();
      asm volatile("" ::: "memory");
      if (s + 3 < nsteps) STAGE(s + 3);

      const char* base  = &smem[(s & 3) * 8192];
      const char* pbase = &smem[PHI_LDS + s * 2048];
      f32x4 p0 = *(const f32x4*)(pbase + off_p0);
      f32x4 p1 = *(const f32x4*)(pbase + off_p1);
      float ph[8] = {p0[0], p0[1], p0[2], p0[3], p1[0], p1[1], p1[2], p1[3]};

      f16x8 bh[4], bl[4];
#pragma unroll
      for (int nt = 0; nt < 4; ++nt) {
        bh[nt] = *(const f16x8*)(base + off_b[nt]);
        bl[nt] = *(const f16x8*)(base + 4096 + off_b[nt]);
      }
      __builtin_amdgcn_s_setprio(1);
#pragma unroll
      for (int mi = 0; mi < 7; ++mi) {
        if (mi >= MT) break;
        f16x8 xh = *(const f16x8*)(base + off_a[mi]);          // broadcast
        f16x8 xl = *(const f16x8*)(base + 4096 + off_a[mi]);   // broadcast
        float v0 = ph[0] * ((float)xh[0] + (float)xl[0]);
        float v1 = ph[1] * ((float)xh[1] + (float)xl[1]);
        float v2 = ph[2] * ((float)xh[2] + (float)xl[2]);
        float v3 = ph[3] * ((float)xh[3] + (float)xl[3]);
        float v4 = ph[4] * ((float)xh[4] + (float)xl[4]);
        float v5 = ph[5] * ((float)xh[5] + (float)xl[5]);
        float v6 = ph[6] * ((float)xh[6] + (float)xl[6]);
        float v7 = ph[7] * ((float)xh[7] + (float)xl[7]);
        auto h0 = __builtin_amdgcn_cvt_pkrtz(v0, v1);
        auto h1 = __builtin_amdgcn_cvt_pkrtz(v2, v3);
        auto h2 = __builtin_amdgcn_cvt_pkrtz(v4, v5);
        auto h3 = __builtin_amdgcn_cvt_pkrtz(v6, v7);
        float r0 = v0 - (float)h0[0], r1 = v1 - (float)h0[1];
        float r2 = v2 - (float)h1[0], r3 = v3 - (float)h1[1];
        float r4 = v4 - (float)h2[0], r5 = v5 - (float)h2[1];
        float r6 = v6 - (float)h3[0], r7 = v7 - (float)h3[1];
        auto e0 = __builtin_amdgcn_cvt_pkrtz(r0, r1);
        auto e1 = __builtin_amdgcn_cvt_pkrtz(r2, r3);
        auto e2 = __builtin_amdgcn_cvt_pkrtz(r4, r5);
        auto e3 = __builtin_amdgcn_cvt_pkrtz(r6, r7);
        u32x4 uh = {__builtin_bit_cast(unsigned int, h0), __builtin_bit_cast(unsigned int, h1),
                    __builtin_bit_cast(unsigned int, h2), __builtin_bit_cast(unsigned int, h3)};
        u32x4 ul = {__builtin_bit_cast(unsigned int, e0), __builtin_bit_cast(unsigned int, e1),
                    __builtin_bit_cast(unsigned int, e2), __builtin_bit_cast(unsigned int, e3)};
        f16x8 ah = __builtin_bit_cast(f16x8, uh);
        f16x8 al = __builtin_bit_cast(f16x8, ul);
#pragma unroll
        for (int nt = 0; nt < 4; ++nt) {
          acc[mi][nt] = __builtin_amdgcn_mfma_f32_16x16x32_f16(ah, bh[nt], acc[mi][nt], 0, 0, 0);
          acc[mi][nt] = __builtin_amdgcn_mfma_f32_16x16x32_f16(ah, bl[nt], acc[mi][nt], 0, 0, 0);
          acc[mi][nt] = __builtin_amdgcn_mfma_f32_16x16x32_f16(al, bh[nt], acc[mi][nt], 0, 0, 0);
        }
      }
      __builtin_amdgcn_s_setprio(0);
    }
#undef STAGE
  }

  // epilogue: pair-symmetric slab write (i<=j<50), float4 over t = lg*4+r
  float* Pc = P + (size_t)blockIdx.x * PSZ;
#pragma unroll
  for (int mi = 0; mi < 7; ++mi) {
    if (mi >= MT) break;
    int i = i0w + mi;
    if (i < 50) {
#pragma unroll
      for (int nt = 0; nt < 4; ++nt) {
        int j = nt * 16 + l15;
        if (j >= i && j < 50) {
          int pb = (i * (101 - i)) / 2 + (j - i);
          *(f32x4*)(Pc + pb * 16 + lg * 4) = acc[mi][nt];
        }
      }
    }
  }
}

// ---------------- Kernel 2: slab reduction (nslabs -> 8 groups) ----------------
__global__ __launch_bounds__(256)
void reduce_a(const float4* __restrict__ P4, int nslabs, float4* __restrict__ part4)
{
  int g = blockIdx.y;                               // 0..7
  int idx = blockIdx.x * 256 + threadIdx.x;         // 20 blocks cover PSZ/4 = 5100
  if (idx >= PSZ / 4) return;
  int per = (nslabs + 7) / 8;
  int c0 = g * per, c1 = c0 + per; if (c1 > nslabs) c1 = nslabs;
  float4 s = make_float4(0.f, 0.f, 0.f, 0.f);
  for (int cc = c0; cc < c1; ++cc) {
    float4 v = P4[(size_t)cc * (PSZ / 4) + idx];
    s.x += v.x; s.y += v.y; s.z += v.z; s.w += v.w;
  }
  part4[(size_t)g * (PSZ / 4) + idx] = s;
}

// ---------------- Kernel 3: finalize (GJ inverse etc.), sums 8 partials inline ------
__device__ __forceinline__ float accv(const float* __restrict__ part, int idx) {
  float s = 0.f;
#pragma unroll
  for (int g = 0; g < 8; ++g) s += part[g * PSZ + idx];
  return s;
}

__global__ __launch_bounds__(256)
void finalize_kernel(const float* __restrict__ part, const float* __restrict__ epsA,
                     const float* __restrict__ epsB, const float* __restrict__ zetA,
                     const float* __restrict__ zetB, float* __restrict__ out)
{
  int t = blockIdx.x;
  int tid = threadIdx.x;
  __shared__ float G[HP1][84];          // [M | I] augmented
  __shared__ float As[HP1][HP1 + 1];
  __shared__ float bs[HP1];
  __shared__ float colk[HP1];
  __shared__ float red[256];
  __shared__ float wmv[HP1];
  __shared__ float rowv[4][HP1 + 1];
  __shared__ float mus[Dd];

  float epsExp = epsA[t] / epsB[t];
  float zetaExp = zetA[t] / zetB[t];

  for (int idx = tid; idx < HP1 * HP1; idx += 256) {
    int i = idx / HP1, j = idx % HP1;
    float a = accv(part, pidx(i, j) * Tt + t);
    As[i][j] = a;
    G[i][j] = epsExp * a + (i == j ? zetaExp : 0.f);
    G[i][41 + j] = (i == j) ? 1.f : 0.f;
  }
  for (int idx = tid; idx < HP1; idx += 256) {
    G[idx][82] = 0.f; G[idx][83] = 0.f;
    bs[idx] = accv(part, pidx(idx, 49) * Tt + t);
  }
  __syncthreads();

  int c = tid % HP1;         // 0..40
  int ig = tid / HP1;        // 0..6; ig<6 active
  int irow0 = ig * 7;

  for (int k = 0; k < HP1; ++k) {
    float pivinv = 1.f / G[k][k];
    if (tid >= 1 && tid <= HP1) G[k][k + tid] *= pivinv;
    if (tid < HP1) colk[tid] = (tid == k) ? 0.f : G[tid][k];
    __syncthreads();
    if (ig < 6) {
      int j = k + 1 + c;
      float pk = G[k][j];
#pragma unroll
      for (int r = 0; r < 7; ++r) {
        int i = irow0 + r;
        if (i < HP1 && i != k) G[i][j] = fmaf(-colk[i], pk, G[i][j]);
      }
    }
    __syncthreads();
  }

  for (int idx = tid; idx < HP1 * HP1; idx += 256) {
    int i = idx / HP1, j = idx % HP1;
    out[OFF_WS + (t * HP1 + i) * HP1 + j] = G[i][41 + j];
  }
  if (tid < HP1) {
    float s = 0.f;
    for (int j = 0; j < HP1; ++j) s += G[tid][41 + j] * bs[j];
    float w = zetaExp * s;
    wmv[tid] = w;
    out[OFF_WM + t * HP1 + tid] = w;
  }
  __syncthreads();
  float lt2 = 0.f;
  for (int idx = tid; idx < HP1 * HP1; idx += 256) {
    int i = idx / HP1, j = idx % HP1;
    lt2 += As[i][j] * G[i][41 + j];
  }
  red[tid] = lt2; __syncthreads();
  for (int s = 128; s > 0; s >>= 1) {
    if (tid < s) red[tid] += red[tid + s];
    __syncthreads();
  }
  float t2v = red[0];
  if (tid < HP1) {
    float w = wmv[tid];
    float aw = 0.f;
    for (int j = 0; j < HP1; ++j) aw += As[tid][j] * wmv[j];
    rowv[0][tid] = w * bs[tid];
    rowv[1][tid] = w * w;
    rowv[2][tid] = G[tid][41 + tid];
    rowv[3][tid] = w * aw;
  }
  __syncthreads();

  float sp = accv(part, pidx(40, 40) * Tt + t);
  float kap = 1000.f + sp;
  float syy = accv(part, pidx(49, 49) * Tt + t);

  if (tid == 0) {
    float wb = 0.f, wn = 0.f, trc = 0.f, quad = 0.f;
    for (int i = 0; i < HP1; ++i) {
      wb += rowv[0][i]; wn += rowv[1][i]; trc += rowv[2][i]; quad += rowv[3][i];
    }
    float t1 = syy - 2.f * wb + quad;
    out[OFF_BG1 + t] = 1.f + sp;
    float rest = 0.f;
    for (int u = t + 1; u < Tt; ++u) rest += accv(part, pidx(40, 40) * Tt + u);
    out[OFF_BG2 + t] = 1.f + rest;            // ALPHA_DP = 1
    out[OFF_KAPPA + t] = kap;
    out[OFF_NU + t] = sp + 100.f;
    out[OFF_ZA + t] = zetA[t] + 0.5f * (float)HP1;
    out[OFF_ZB + t] = zetB[t] + 0.5f * (wn + trc);
    out[OFF_EA + t] = epsA[t] + 0.5f * sp;
    out[OFF_EB + t] = epsB[t] + 0.5f * (t1 + t2v);
  }
  if (tid < Dd) {
    float m = accv(part, pidx(40, 41 + tid) * Tt + t) / kap;
    mus[tid] = m;
    out[OFF_MU + tid * Tt + t] = m;
  }
  __syncthreads();
  if (tid < Dd * Dd) {
    int i = tid / Dd, j = tid % Dd;
    float S = accv(part, pidx(41 + i, 41 + j) * Tt + t);
    float v = (i == j ? 500.f : 0.f) + S - kap * mus[i] * mus[j];
    out[OFF_PSI + (i * Dd + j) * Tt + t] = v;
  }
}

extern "C" void kernel_launch(void* const* d_in, const int* in_sizes, int n_in,
                              void* d_out, int out_size, void* d_ws, size_t ws_size,
                              hipStream_t stream) {
  const float* Phi = (const float*)d_in[1];
  const float* Xd  = (const float*)d_in[2];
  const float* Yd  = (const float*)d_in[3];
  const float* W   = (const float*)d_in[4];
  const float* bb  = (const float*)d_in[5];
  const float* eA  = (const float*)d_in[6];
  const float* eB  = (const float*)d_in[7];
  const float* zA  = (const float*)d_in[8];
  const float* zB  = (const float*)d_in[9];
  float* out = (float*)d_out;
  float* ws  = (float*)d_ws;

  unsigned short* XeHi = (unsigned short*)(ws + XEH_OFF);
  unsigned short* XeLo = (unsigned short*)(ws + XEL_OFF);
  float* PhiT = ws + PHIT_OFF;
  float* part = ws + PART_OFF;
  float* P    = ws + P_OFF;

  // slab count bounded by workspace (deterministic, graph-safe);
  // grid-stride in gram_mfma covers all KCMAX chunks regardless
  long maxSlabs = ((long)(ws_size / 4) - (long)P_OFF) / PSZ;
  int grid1 = (int)(maxSlabs < KCMAX ? maxSlabs : KCMAX);   // 391 when ws >= 64.6MB
  if (grid1 < 1) grid1 = 1;

  hipLaunchKernelGGL(elm_expand, dim3((Nn + 63) / 64), dim3(256), 0, stream,
                     Phi, Xd, Yd, W, bb, XeHi, XeLo, PhiT);
  hipLaunchKernelGGL(gram_mfma, dim3(grid1), dim3(512), 0, stream,
                     PhiT, XeHi, XeLo, P);
  hipLaunchKernelGGL(reduce_a, dim3(20, 8), dim3(256), 0, stream,
                     (const float4*)P, grid1, (float4*)part);
  hipLaunchKernelGGL(finalize_kernel, dim3(Tt), dim3(256), 0, stream,
                     part, eA, eB, zA, zB, out);
}

// Round 8
// 183.932 us; speedup vs baseline: 1.0222x; 1.0222x over previous
//
#include <hip/hip_runtime.h>

#define Nn 100000
#define Tt 16
#define Dd 8
#define Hh 40
#define HP1 41

// ---- gram geometry (fixed) ----
#define SPC 8                  // 32-k steps per chunk
#define CH  (32 * SPC)         // 256 n per chunk
#define KCMAX ((Nn + CH - 1) / CH)    // 391 chunks

// ---- pair-symmetric slab: i<=j<50 pairs x 16 t ----
#define NPAIR 1275
#define PSZ (NPAIR * 16)       // 20400 floats per slab

// ---- workspace layout (float slots) ----
#define XEH_OFF  0                     // XeHi [64][Nn] f16 -> 32*Nn float slots
#define XEL_OFF  (XEH_OFF + 32 * Nn)   // XeLo [64][Nn] f16
#define PHIT_OFF (XEL_OFF + 32 * Nn)   // PhiT [16][Nn] f32
#define PART_OFF (PHIT_OFF + 16 * Nn)  // 8 * PSZ partials
#define P_OFF    (PART_OFF + 8 * PSZ)  // slabs

// output offsets (flat, return order)
#define OFF_BG1   0
#define OFF_BG2   16
#define OFF_MU    32
#define OFF_KAPPA 160
#define OFF_NU    176
#define OFF_PSI   192
#define OFF_WM    1216
#define OFF_WS    1872
#define OFF_ZA    28768
#define OFF_ZB    28784
#define OFF_EA    28800
#define OFF_EB    28816

typedef _Float16 f16x8 __attribute__((ext_vector_type(8)));
typedef float f32x4 __attribute__((ext_vector_type(4)));
typedef unsigned int u32x4 __attribute__((ext_vector_type(4)));

__device__ __forceinline__ int pidx(int i, int j) {
  if (i > j) { int tmp = i; i = j; j = tmp; }
  return (i * (2 * 50 - i + 1)) / 2 + (j - i);
}

// ---------------- Kernel 0: ELM expansion -> XeHi/XeLo planes + PhiT ------
// Xe row layout c: [h0..h39, 1, x0..x7, y, 0...0] (c=50..63 zero)
__global__ __launch_bounds__(256)
void elm_expand(const float* __restrict__ Phi, const float* __restrict__ Xd,
                const float* __restrict__ Yd, const float* __restrict__ W,
                const float* __restrict__ bb,
                unsigned short* __restrict__ XeHi, unsigned short* __restrict__ XeLo,
                float* __restrict__ PhiT)
{
  __shared__ float sW[Dd * Hh];
  __shared__ float sb[Hh];
  __shared__ float xs[64][9];
  __shared__ float ys[64];
  __shared__ float hrow[64][41];
  __shared__ float pt[16][68];
  int tid = threadIdx.x;
  int n0 = blockIdx.x * 64;

  for (int i = tid; i < Dd * Hh; i += 256) sW[i] = W[i];
  if (tid < Hh) sb[tid] = bb[tid];
  if (tid < 128) {
    int nl = tid >> 1, h4 = (tid & 1) * 4;
    int gn = n0 + nl;
    float4 v = (gn < Nn) ? *(const float4*)(Xd + (size_t)gn * 8 + h4)
                         : make_float4(0.f, 0.f, 0.f, 0.f);
    xs[nl][h4 + 0] = v.x; xs[nl][h4 + 1] = v.y;
    xs[nl][h4 + 2] = v.z; xs[nl][h4 + 3] = v.w;
  }
  if (tid < 64) { int gn = n0 + tid; ys[tid] = (gn < Nn) ? Yd[gn] : 0.f; }
  {
    int nl = tid >> 2, q = tid & 3;
    int gn = n0 + nl;
    float4 v = (gn < Nn) ? *(const float4*)(Phi + (size_t)gn * 16 + q * 4)
                         : make_float4(0.f, 0.f, 0.f, 0.f);
    pt[q * 4 + 0][nl] = v.x; pt[q * 4 + 1][nl] = v.y;
    pt[q * 4 + 2][nl] = v.z; pt[q * 4 + 3][nl] = v.w;
  }
  __syncthreads();
  // sigmoids: thread -> (n, 10 h's)
  {
    int nl = tid >> 2, hq = (tid & 3) * 10;
    for (int hh = 0; hh < 10; ++hh) {
      int h = hq + hh;
      float z = sb[h];
#pragma unroll
      for (int d = 0; d < 8; ++d) z = fmaf(xs[nl][d], sW[d * Hh + h], z);
      hrow[nl][h] = 1.f / (1.f + __expf(-z));
    }
  }
  __syncthreads();
  // PhiT write: thread (t = tid&15, nq = tid>>4) -> float4
  {
    int t = tid & 15, nq = tid >> 4;
    int gn = n0 + nq * 4;
    if (gn < Nn) {
      float4 v = make_float4(pt[t][nq * 4 + 0], pt[t][nq * 4 + 1],
                             pt[t][nq * 4 + 2], pt[t][nq * 4 + 3]);
      *(float4*)(PhiT + (size_t)t * Nn + gn) = v;
    }
  }
  // Xe hi/lo planes: thread (c = tid>>2, seg = tid&3) covers 16 n's
  {
    int cidx = tid >> 2, seg = tid & 3;
    int nl0 = seg * 16;
    float vv[16];
#pragma unroll
    for (int j = 0; j < 16; ++j) {
      int n = nl0 + j;
      float v;
      if (cidx < Hh) v = hrow[n][cidx];
      else if (cidx == 40) v = 1.f;
      else if (cidx < 49) v = xs[n][cidx - 41];
      else if (cidx == 49) v = ys[n];
      else v = 0.f;
      vv[j] = v;
    }
    unsigned short hs[16], ls[16];
#pragma unroll
    for (int j = 0; j < 16; ++j) {
      _Float16 h = (_Float16)vv[j];
      float r = vv[j] - (float)h;
      _Float16 lo = (_Float16)r;
      hs[j] = __builtin_bit_cast(unsigned short, h);
      ls[j] = __builtin_bit_cast(unsigned short, lo);
    }
#pragma unroll
    for (int q2 = 0; q2 < 2; ++q2) {
      int gn = n0 + nl0 + q2 * 8;
      if (gn < Nn) {
        uint4 uh, ul;
        uh.x = hs[q2*8+0] | ((unsigned)hs[q2*8+1] << 16);
        uh.y = hs[q2*8+2] | ((unsigned)hs[q2*8+3] << 16);
        uh.z = hs[q2*8+4] | ((unsigned)hs[q2*8+5] << 16);
        uh.w = hs[q2*8+6] | ((unsigned)hs[q2*8+7] << 16);
        ul.x = ls[q2*8+0] | ((unsigned)ls[q2*8+1] << 16);
        ul.y = ls[q2*8+2] | ((unsigned)ls[q2*8+3] << 16);
        ul.z = ls[q2*8+4] | ((unsigned)ls[q2*8+5] << 16);
        ul.w = ls[q2*8+6] | ((unsigned)ls[q2*8+7] << 16);
        *(uint4*)(XeHi + (size_t)cidx * Nn + gn) = uh;
        *(uint4*)(XeLo + (size_t)cidx * Nn + gn) = ul;
      }
    }
  }
}

// ---------------- Kernel 1: MFMA Gram, 4 small blocks per chunk ----------------
// Block (bM, g): bM = blockIdx.x&3 owns i in [13bM, 13bM+13); g = chunk group,
// grid-strides chunks cc = g, g+G, ... (acc persists; one slab write per block).
// 4 waves: w0 owns 4 mi, w1-3 own 3 mi each (13 total), all 4 N-tiles.
// A rows are a SUBSET of B rows: staged B hi/lo planes serve both operands.
// LDS (48KB): 4-deep ring x 8KB (Bhi[64][32k]f16 @0, Blo @4096) + phi
// [8 steps][16 t][32 k]f32 @32768 (16KB, staged once per chunk).
// Swizzles (source-preswizzled, linear LDS dest; same involution on read):
//   B/A granule' = g ^ ((row>>1)&3)  -> exact 2-way bank aliasing (free, m136)
//   phi granule' = g ^ (t&7)
// Pipeline: phi + stages 0..2 in prologue; loop s: s_waitcnt vmcnt(4|2|0),
// s_barrier (stages s+1,s+2 in flight across it), STAGE(s+3), compute.
__device__ __forceinline__ void gload16(const void* g, void* l) {
  __builtin_amdgcn_global_load_lds(
      (const __attribute__((address_space(1))) unsigned int*)g,
      (__attribute__((address_space(3))) unsigned int*)l, 16, 0, 0);
}

#define PHI_LDS 32768                       // byte offset of phi region
#define LDS_BYTES (PHI_LDS + 16 * CH * 4)   // 32768 + 16384 = 49152

__global__ __launch_bounds__(256, 3)
void gram_mfma(const float* __restrict__ PhiT,
               const unsigned short* __restrict__ XeHi,
               const unsigned short* __restrict__ XeLo,
               float* __restrict__ P, int G)
{
  __shared__ __align__(16) char smem[LDS_BYTES];

  int tid = threadIdx.x;
  int l = tid & 63, w = tid >> 6;
  int l15 = l & 15, lg = l >> 4;
  int bM = blockIdx.x & 3, g = blockIdx.x >> 2;
  int i0 = bM * 13;

  // wave mi ranges: w0: 0..3 (4 tiles), w1: 4..6, w2: 7..9, w3: 10..12
  int mbase = (w == 0) ? 0 : (1 + 3 * w);
  int MT = (w == 0) ? 4 : 3;

  // ---- static read offsets (bytes) ----
  int off_b[4];
#pragma unroll
  for (int nt = 0; nt < 4; ++nt) {
    int j = l15 + 16 * nt;
    off_b[nt] = j * 64 + 16 * (lg ^ ((j >> 1) & 3));
  }
  int off_a[4];
#pragma unroll
  for (int mi = 0; mi < 4; ++mi) {
    int i = i0 + mbase + mi;       // <= 52; rows >= 50 are exact zeros
    off_a[mi] = i * 64 + 16 * (lg ^ ((i >> 1) & 3));
  }
  int off_p0 = PHI_LDS + l15 * 128 + 16 * ((2 * lg) ^ (l15 & 7));
  int off_p1 = PHI_LDS + l15 * 128 + 16 * ((2 * lg + 1) ^ (l15 & 7));

  // stage decode: thread tid stages granule tid (Hi) + 256+tid (Lo); same row
  int srow = tid >> 2;
  int ssl = (tid & 3) ^ ((srow >> 1) & 3);

  f32x4 acc[4][4];
#pragma unroll
  for (int mi = 0; mi < 4; ++mi)
#pragma unroll
    for (int nt = 0; nt < 4; ++nt) acc[mi][nt] = (f32x4){0.f, 0.f, 0.f, 0.f};

  for (int cc = g; cc < KCMAX; cc += G) {
    int n0 = cc * CH;
    int rem = Nn - n0; if (rem > CH) rem = CH;
    int nsteps = rem >> 5;         // 8 (or 5 for the last chunk)

    // protect LDS reuse across chunk iterations (harmless on first)
    __builtin_amdgcn_s_barrier();
    asm volatile("" ::: "memory");

    const char* gH = (const char*)(XeHi + (size_t)srow * Nn + n0 + 8 * ssl);
    const char* gL = (const char*)(XeLo + (size_t)srow * Nn + n0 + 8 * ssl);
#define STAGE(sx) do {                                                    \
    gload16(gH + (size_t)(sx) * 64, &smem[(((sx) & 3) * 8192) + tid * 16]);\
    gload16(gL + (size_t)(sx) * 64,                                       \
            &smem[(((sx) & 3) * 8192) + 4096 + tid * 16]);                \
  } while (0)

    // phi prologue: [SPC][16][32] f32 = 1024 granules, 4 per thread.
    // Clamp source n-base: last chunk has nsteps<SPC; steps >= nsteps are
    // never read, but keep the staged read in-bounds (dup data, zero cost).
#pragma unroll
    for (int q = 0; q < 4; ++q) {
      int gp = tid + q * 256;
      int s = gp >> 7, t = (gp & 127) >> 3, sl = gp & 7;
      int nsrc = n0 + s * 32;
      if (nsrc > Nn - 32) nsrc = Nn - 32;
      gload16(PhiT + (size_t)t * Nn + nsrc + 4 * (sl ^ (t & 7)),
              &smem[PHI_LDS + gp * 16]);
    }
    STAGE(0);
    if (nsteps > 1) STAGE(1);
    if (nsteps > 2) STAGE(2);

    for (int s = 0; s < nsteps; ++s) {
      // counted wait (2 loads per stage): stages s+1,s+2 stay in flight
      int out = nsteps - 1 - s; if (out > 2) out = 2;
      if (out == 2)      asm volatile("s_waitcnt vmcnt(4)" ::: "memory");
      else if (out == 1) asm volatile("s_waitcnt vmcnt(2)" ::: "memory");
      else               asm volatile("s_waitcnt vmcnt(0)" ::: "memory");
      __builtin_amdgcn_s_barrier();
      asm volatile("" ::: "memory");
      if (s + 3 < nsteps) STAGE(s + 3);

      const char* base  = &smem[(s & 3) * 8192];
      const char* pbase = &smem[s * 2048];       // + PHI_LDS folded in off_p*
      f32x4 p0 = *(const f32x4*)(pbase + off_p0);
      f32x4 p1 = *(const f32x4*)(pbase + off_p1);
      float ph[8] = {p0[0], p0[1], p0[2], p0[3], p1[0], p1[1], p1[2], p1[3]};

      f16x8 bh[4], bl[4];
#pragma unroll
      for (int nt = 0; nt < 4; ++nt) {
        bh[nt] = *(const f16x8*)(base + off_b[nt]);
        bl[nt] = *(const f16x8*)(base + 4096 + off_b[nt]);
      }
      __builtin_amdgcn_s_setprio(1);
#pragma unroll
      for (int mi = 0; mi < 4; ++mi) {
        if (mi >= MT) break;
        f16x8 xh = *(const f16x8*)(base + off_a[mi]);          // broadcast
        f16x8 xl = *(const f16x8*)(base + 4096 + off_a[mi]);   // broadcast
        float v0 = ph[0] * ((float)xh[0] + (float)xl[0]);
        float v1 = ph[1] * ((float)xh[1] + (float)xl[1]);
        float v2 = ph[2] * ((float)xh[2] + (float)xl[2]);
        float v3 = ph[3] * ((float)xh[3] + (float)xl[3]);
        float v4 = ph[4] * ((float)xh[4] + (float)xl[4]);
        float v5 = ph[5] * ((float)xh[5] + (float)xl[5]);
        float v6 = ph[6] * ((float)xh[6] + (float)xl[6]);
        float v7 = ph[7] * ((float)xh[7] + (float)xl[7]);
        auto h0 = __builtin_amdgcn_cvt_pkrtz(v0, v1);
        auto h1 = __builtin_amdgcn_cvt_pkrtz(v2, v3);
        auto h2 = __builtin_amdgcn_cvt_pkrtz(v4, v5);
        auto h3 = __builtin_amdgcn_cvt_pkrtz(v6, v7);
        float r0 = v0 - (float)h0[0], r1 = v1 - (float)h0[1];
        float r2 = v2 - (float)h1[0], r3 = v3 - (float)h1[1];
        float r4 = v4 - (float)h2[0], r5 = v5 - (float)h2[1];
        float r6 = v6 - (float)h3[0], r7 = v7 - (float)h3[1];
        auto e0 = __builtin_amdgcn_cvt_pkrtz(r0, r1);
        auto e1 = __builtin_amdgcn_cvt_pkrtz(r2, r3);
        auto e2 = __builtin_amdgcn_cvt_pkrtz(r4, r5);
        auto e3 = __builtin_amdgcn_cvt_pkrtz(r6, r7);
        u32x4 uh = {__builtin_bit_cast(unsigned int, h0), __builtin_bit_cast(unsigned int, h1),
                    __builtin_bit_cast(unsigned int, h2), __builtin_bit_cast(unsigned int, h3)};
        u32x4 ul = {__builtin_bit_cast(unsigned int, e0), __builtin_bit_cast(unsigned int, e1),
                    __builtin_bit_cast(unsigned int, e2), __builtin_bit_cast(unsigned int, e3)};
        f16x8 ah = __builtin_bit_cast(f16x8, uh);
        f16x8 al = __builtin_bit_cast(f16x8, ul);
#pragma unroll
        for (int nt = 0; nt < 4; ++nt) {
          acc[mi][nt] = __builtin_amdgcn_mfma_f32_16x16x32_f16(ah, bh[nt], acc[mi][nt], 0, 0, 0);
          acc[mi][nt] = __builtin_amdgcn_mfma_f32_16x16x32_f16(ah, bl[nt], acc[mi][nt], 0, 0, 0);
          acc[mi][nt] = __builtin_amdgcn_mfma_f32_16x16x32_f16(al, bh[nt], acc[mi][nt], 0, 0, 0);
        }
      }
      __builtin_amdgcn_s_setprio(0);
    }
#undef STAGE
  }

  // epilogue: pair-symmetric slab write (i<=j<50); 4 bM blocks of a group
  // write disjoint pair ranges of slab g (owner = block containing row i)
  float* Pc = P + (size_t)g * PSZ;
#pragma unroll
  for (int mi = 0; mi < 4; ++mi) {
    if (mi >= MT) break;
    int i = i0 + mbase + mi;
    if (i < 50) {
#pragma unroll
      for (int nt = 0; nt < 4; ++nt) {
        int j = nt * 16 + l15;
        if (j >= i && j < 50) {
          int pb = (i * (101 - i)) / 2 + (j - i);
          *(f32x4*)(Pc + pb * 16 + lg * 4) = acc[mi][nt];
        }
      }
    }
  }
}

// ---------------- Kernel 2: slab reduction (nslabs -> 8 groups) ----------------
__global__ __launch_bounds__(256)
void reduce_a(const float4* __restrict__ P4, int nslabs, float4* __restrict__ part4)
{
  int g = blockIdx.y;                               // 0..7
  int idx = blockIdx.x * 256 + threadIdx.x;         // 20 blocks cover PSZ/4 = 5100
  if (idx >= PSZ / 4) return;
  int per = (nslabs + 7) / 8;
  int c0 = g * per, c1 = c0 + per; if (c1 > nslabs) c1 = nslabs;
  float4 s = make_float4(0.f, 0.f, 0.f, 0.f);
  for (int cc = c0; cc < c1; ++cc) {
    float4 v = P4[(size_t)cc * (PSZ / 4) + idx];
    s.x += v.x; s.y += v.y; s.z += v.z; s.w += v.w;
  }
  part4[(size_t)g * (PSZ / 4) + idx] = s;
}

// ---------------- Kernel 3: finalize (GJ inverse etc.), sums 8 partials inline ------
__device__ __forceinline__ float accv(const float* __restrict__ part, int idx) {
  float s = 0.f;
#pragma unroll
  for (int g = 0; g < 8; ++g) s += part[g * PSZ + idx];
  return s;
}

__global__ __launch_bounds__(256)
void finalize_kernel(const float* __restrict__ part, const float* __restrict__ epsA,
                     const float* __restrict__ epsB, const float* __restrict__ zetA,
                     const float* __restrict__ zetB, float* __restrict__ out)
{
  int t = blockIdx.x;
  int tid = threadIdx.x;
  __shared__ float G[HP1][84];          // [M | I] augmented
  __shared__ float As[HP1][HP1 + 1];
  __shared__ float bs[HP1];
  __shared__ float colk[HP1];
  __shared__ float red[256];
  __shared__ float wmv[HP1];
  __shared__ float rowv[4][HP1 + 1];
  __shared__ float mus[Dd];

  float epsExp = epsA[t] / epsB[t];
  float zetaExp = zetA[t] / zetB[t];

  for (int idx = tid; idx < HP1 * HP1; idx += 256) {
    int i = idx / HP1, j = idx % HP1;
    float a = accv(part, pidx(i, j) * Tt + t);
    As[i][j] = a;
    G[i][j] = epsExp * a + (i == j ? zetaExp : 0.f);
    G[i][41 + j] = (i == j) ? 1.f : 0.f;
  }
  for (int idx = tid; idx < HP1; idx += 256) {
    G[idx][82] = 0.f; G[idx][83] = 0.f;
    bs[idx] = accv(part, pidx(idx, 49) * Tt + t);
  }
  __syncthreads();

  int c = tid % HP1;         // 0..40
  int ig = tid / HP1;        // 0..6; ig<6 active
  int irow0 = ig * 7;

  for (int k = 0; k < HP1; ++k) {
    float pivinv = 1.f / G[k][k];
    if (tid >= 1 && tid <= HP1) G[k][k + tid] *= pivinv;
    if (tid < HP1) colk[tid] = (tid == k) ? 0.f : G[tid][k];
    __syncthreads();
    if (ig < 6) {
      int j = k + 1 + c;
      float pk = G[k][j];
#pragma unroll
      for (int r = 0; r < 7; ++r) {
        int i = irow0 + r;
        if (i < HP1 && i != k) G[i][j] = fmaf(-colk[i], pk, G[i][j]);
      }
    }
    __syncthreads();
  }

  for (int idx = tid; idx < HP1 * HP1; idx += 256) {
    int i = idx / HP1, j = idx % HP1;
    out[OFF_WS + (t * HP1 + i) * HP1 + j] = G[i][41 + j];
  }
  if (tid < HP1) {
    float s = 0.f;
    for (int j = 0; j < HP1; ++j) s += G[tid][41 + j] * bs[j];
    float w = zetaExp * s;
    wmv[tid] = w;
    out[OFF_WM + t * HP1 + tid] = w;
  }
  __syncthreads();
  float lt2 = 0.f;
  for (int idx = tid; idx < HP1 * HP1; idx += 256) {
    int i = idx / HP1, j = idx % HP1;
    lt2 += As[i][j] * G[i][41 + j];
  }
  red[tid] = lt2; __syncthreads();
  for (int s = 128; s > 0; s >>= 1) {
    if (tid < s) red[tid] += red[tid + s];
    __syncthreads();
  }
  float t2v = red[0];
  if (tid < HP1) {
    float w = wmv[tid];
    float aw = 0.f;
    for (int j = 0; j < HP1; ++j) aw += As[tid][j] * wmv[j];
    rowv[0][tid] = w * bs[tid];
    rowv[1][tid] = w * w;
    rowv[2][tid] = G[tid][41 + tid];
    rowv[3][tid] = w * aw;
  }
  __syncthreads();

  float sp = accv(part, pidx(40, 40) * Tt + t);
  float kap = 1000.f + sp;
  float syy = accv(part, pidx(49, 49) * Tt + t);

  if (tid == 0) {
    float wb = 0.f, wn = 0.f, trc = 0.f, quad = 0.f;
    for (int i = 0; i < HP1; ++i) {
      wb += rowv[0][i]; wn += rowv[1][i]; trc += rowv[2][i]; quad += rowv[3][i];
    }
    float t1 = syy - 2.f * wb + quad;
    out[OFF_BG1 + t] = 1.f + sp;
    float rest = 0.f;
    for (int u = t + 1; u < Tt; ++u) rest += accv(part, pidx(40, 40) * Tt + u);
    out[OFF_BG2 + t] = 1.f + rest;            // ALPHA_DP = 1
    out[OFF_KAPPA + t] = kap;
    out[OFF_NU + t] = sp + 100.f;
    out[OFF_ZA + t] = zetA[t] + 0.5f * (float)HP1;
    out[OFF_ZB + t] = zetB[t] + 0.5f * (wn + trc);
    out[OFF_EA + t] = epsA[t] + 0.5f * sp;
    out[OFF_EB + t] = epsB[t] + 0.5f * (t1 + t2v);
  }
  if (tid < Dd) {
    float m = accv(part, pidx(40, 41 + tid) * Tt + t) / kap;
    mus[tid] = m;
    out[OFF_MU + tid * Tt + t] = m;
  }
  __syncthreads();
  if (tid < Dd * Dd) {
    int i = tid / Dd, j = tid % Dd;
    float S = accv(part, pidx(41 + i, 41 + j) * Tt + t);
    float v = (i == j ? 500.f : 0.f) + S - kap * mus[i] * mus[j];
    out[OFF_PSI + (i * Dd + j) * Tt + t] = v;
  }
}

extern "C" void kernel_launch(void* const* d_in, const int* in_sizes, int n_in,
                              void* d_out, int out_size, void* d_ws, size_t ws_size,
                              hipStream_t stream) {
  const float* Phi = (const float*)d_in[1];
  const float* Xd  = (const float*)d_in[2];
  const float* Yd  = (const float*)d_in[3];
  const float* W   = (const float*)d_in[4];
  const float* bb  = (const float*)d_in[5];
  const float* eA  = (const float*)d_in[6];
  const float* eB  = (const float*)d_in[7];
  const float* zA  = (const float*)d_in[8];
  const float* zB  = (const float*)d_in[9];
  float* out = (float*)d_out;
  float* ws  = (float*)d_ws;

  unsigned short* XeHi = (unsigned short*)(ws + XEH_OFF);
  unsigned short* XeLo = (unsigned short*)(ws + XEL_OFF);
  float* PhiT = ws + PHIT_OFF;
  float* part = ws + PART_OFF;
  float* P    = ws + P_OFF;

  // slab-group count bounded by workspace (deterministic, graph-safe);
  // each group = 4 bM blocks sharing one slab; grid-stride covers all chunks
  long maxSlabs = ((long)(ws_size / 4) - (long)P_OFF) / PSZ;
  int G = (int)(maxSlabs < KCMAX ? maxSlabs : KCMAX);   // 391 when ws >= 65MB
  if (G < 1) G = 1;

  hipLaunchKernelGGL(elm_expand, dim3((Nn + 63) / 64), dim3(256), 0, stream,
                     Phi, Xd, Yd, W, bb, XeHi, XeLo, PhiT);
  hipLaunchKernelGGL(gram_mfma, dim3(4 * G), dim3(256), 0, stream,
                     PhiT, XeHi, XeLo, P, G);
  hipLaunchKernelGGL(reduce_a, dim3(20, 8), dim3(256), 0, stream,
                     (const float4*)P, G, (float4*)part);
  hipLaunchKernelGGL(finalize_kernel, dim3(Tt), dim3(256), 0, stream,
                     part, eA, eB, zA, zB, out);
}